// Round 1
// baseline (97898.077 us; speedup 1.0000x reference)
//
#include <hip/hip_runtime.h>
#include <cstddef>
#include <cstdint>

#define NODE 207
#define HID 16
#define BATCH 64
#define TSTEPS 12
#define HIDDEN 6624            // NODE*HID*2
#define K_IH 16560             // NODE*HID*5
#define K_IH4 4140             // K_IH/4
#define H4 1656                // HIDDEN/4

// RNN grid: 768 blocks = exactly 3 blocks/CU on 256 CUs (CU-balanced).
// Co-residency guaranteed: LDS 26.5KB*3=79.5KB<160KB, __launch_bounds__(256,3)
// caps VGPR<=170 so 12 waves/CU fit. 3072 waves total.
#define RNN_BLOCKS 768
#define RNN_WAVES  3072

// ---------------------------------------------------------------------------
// Kernel A: build transposed input inpT (K_IH, 64) for outer step t.
// One block per (b, n). inpT[k*64 + b]. (unchanged — ~trivial cost)
// ---------------------------------------------------------------------------
__global__ __launch_bounds__(256) void build_inp_kernel(
    const float* __restrict__ spline,   // (12,64,207,2)
    const float* __restrict__ hz,       // (64,6624)
    const float* __restrict__ Wf,       // (16,32)
    const float* __restrict__ bf,       // (32,)
    const float* __restrict__ Wg,       // (16,256)
    const float* __restrict__ bg,       // (256,)
    const float* __restrict__ conv_w,   // (16,)
    float* __restrict__ inpT,           // (16560,64)
    int t)
{
    const int bn = blockIdx.x;
    const int n = bn % NODE;
    const int b = bn / NODE;
    const int tid = threadIdx.x;

    __shared__ float shz[32];
    __shared__ float sf[32];
    __shared__ float sg[256];

    if (tid < 32) shz[tid] = hz[(size_t)b * HIDDEN + n * 32 + tid];
    __syncthreads();

    {
        float accg = bg[tid];
        #pragma unroll
        for (int i = 0; i < 16; ++i)
            accg = fmaf(shz[2 * i + 1], Wg[i * 256 + tid], accg);
        sg[tid] = tanhf(accg);
    }
    if (tid < 32) {
        float accf = bf[tid];
        #pragma unroll
        for (int i = 0; i < 16; ++i)
            accf = fmaf(shz[2 * i], Wf[i * 32 + tid], accf);
        float fv = tanhf(accf);
        sf[tid] = fv;
        int i2 = tid >> 1, kk = tid & 1;
        int kf = 3312 + n * 64 + i2 * 4 + kk * 2;      // s = 0
        inpT[(size_t)kf * 64 + b] = fv;
    } else if (tid < 48) {
        int i = tid - 32;
        float v = spline[((((size_t)t * BATCH + b) * NODE + n) * 2) + 1];
        inpT[(size_t)(i * NODE + n) * 64 + b] = conv_w[i] * v;
    }
    __syncthreads();
    if (tid < 32) {
        int i2 = tid >> 1, kk = tid & 1;
        float acc = 0.f;
        #pragma unroll
        for (int j = 0; j < 16; ++j)
            acc = fmaf(sg[i2 * 16 + j], sf[j * 2 + kk], acc);
        int kfg = 3312 + n * 64 + i2 * 4 + kk * 2 + 1; // s = 1
        inpT[(size_t)kfg * 64 + b] = acc;
    }
}

// ---------------------------------------------------------------------------
// Kernel A2: pre[b][j] = b_ih[j] + b_hh[j]  (biases folded once; gemm adds on
// top via atomicAdd; rnn then reads a single fused value per row).
// ---------------------------------------------------------------------------
__global__ __launch_bounds__(256) void init_pre_kernel(
    const float* __restrict__ b_ih, const float* __restrict__ b_hh,
    float* __restrict__ pre)
{
    const int j = blockIdx.x * 256 + threadIdx.x;
    if (j < HIDDEN) {
        const float v = b_ih[j] + b_hh[j];
        for (int b = 0; b < BATCH; ++b) pre[(size_t)b * HIDDEN + j] = v;
    }
}

// ---------------------------------------------------------------------------
// Kernel B: pre[b][j] += sum_k inp[b,k] * W_ih[j,k]. (unchanged)
// ---------------------------------------------------------------------------
__global__ __launch_bounds__(256) void gemm_ih_kernel(
    const float* __restrict__ Wih,      // (6624,16560)
    const float* __restrict__ inpT,     // (16560,64)
    float* __restrict__ pre)            // (64,6624), pre-initialized w/ biases
{
    const int jt = blockIdx.x >> 3;     // 0..206
    const int kc = blockIdx.x & 7;      // 0..7
    const int j0 = jt * 32;
    const int tid = threadIdx.x;
    const int b = tid & 63;
    const int p = __builtin_amdgcn_readfirstlane(tid >> 6);
    const int q = kc * 4 + p;           // 0..31

    float acc[32];
    #pragma unroll
    for (int jj = 0; jj < 32; ++jj) acc[jj] = 0.f;

    for (int g = q; g < K_IH4; g += 32) {
        const int k = g * 4;
        const float v0 = inpT[(size_t)(k + 0) * 64 + b];
        const float v1 = inpT[(size_t)(k + 1) * 64 + b];
        const float v2 = inpT[(size_t)(k + 2) * 64 + b];
        const float v3 = inpT[(size_t)(k + 3) * 64 + b];
        #pragma unroll
        for (int jj = 0; jj < 32; ++jj) {
            const float4 w = *reinterpret_cast<const float4*>(
                Wih + (size_t)(j0 + jj) * K_IH + k);
            acc[jj] = fmaf(w.x, v0, fmaf(w.y, v1, fmaf(w.z, v2, fmaf(w.w, v3, acc[jj]))));
        }
    }

    __shared__ float red[4][32][65];
    #pragma unroll
    for (int jj = 0; jj < 32; ++jj) red[p][jj][b] = acc[jj];
    __syncthreads();

    for (int idx = tid; idx < 2048; idx += 256) {
        const int jj = idx & 31;
        const int b2 = idx >> 5;
        const float s = red[0][jj][b2] + red[1][jj][b2] + red[2][jj][b2] + red[3][jj][b2];
        atomicAdd(pre + (size_t)b2 * HIDDEN + j0 + jj, s);
    }
}

// ---------------------------------------------------------------------------
// Grid barrier: flag-array, no contended RMW. Each block release-stores its
// epoch into its own 64B-padded slot; all 256 threads poll 3 flags each with
// relaxed agent-scope loads (bypass stale caches), then one acquire-style
// fence + __syncthreads. Epochs are monotone across the 12 launches.
// ---------------------------------------------------------------------------
__device__ __forceinline__ void grid_barrier(unsigned int* flags, unsigned int e)
{
    __syncthreads();                    // all waves of this block done storing h_b
    if (threadIdx.x == 0) {
        __threadfence();                // agent-scope release of this block's hz stores
        __hip_atomic_store(flags + (size_t)blockIdx.x * 16, e,
                           __ATOMIC_RELEASE, __HIP_MEMORY_SCOPE_AGENT);
    }
    for (int i = threadIdx.x; i < RNN_BLOCKS; i += 256) {
        while (__hip_atomic_load(flags + (size_t)i * 16,
                                 __ATOMIC_RELAXED, __HIP_MEMORY_SCOPE_AGENT) < e)
            __builtin_amdgcn_s_sleep(1);
    }
    __threadfence();                    // make remote hz stores visible before reads
    __syncthreads();
}

// ---------------------------------------------------------------------------
// NR rows per wave, interleaved: NR independent global-load streams sharing
// one LDS h-read per k-chunk; 4*NR accumulators of ILP; pre prefetched early.
// ---------------------------------------------------------------------------
template<int NR>
__device__ __forceinline__ void do_rows(const float4* __restrict__ W4, int j0,
                                        const float4* sh4, int lane,
                                        const float* __restrict__ pre_b,
                                        float* hz_b)
{
    float pv[NR];
    #pragma unroll
    for (int r = 0; r < NR; ++r) pv[r] = (lane == 0) ? pre_b[j0 + r] : 0.f;

    const float4* Wr[NR];
    #pragma unroll
    for (int r = 0; r < NR; ++r) Wr[r] = W4 + (size_t)(j0 + r) * H4;

    float4 acc[NR];
    #pragma unroll
    for (int r = 0; r < NR; ++r) acc[r] = make_float4(0.f, 0.f, 0.f, 0.f);

    #pragma unroll 5
    for (int it = 0; it < 25; ++it) {
        const int idx = it * 64 + lane;
        const float4 h = sh4[idx];
        #pragma unroll
        for (int r = 0; r < NR; ++r) {
            const float4 w = Wr[r][idx];
            acc[r].x = fmaf(w.x, h.x, acc[r].x);
            acc[r].y = fmaf(w.y, h.y, acc[r].y);
            acc[r].z = fmaf(w.z, h.z, acc[r].z);
            acc[r].w = fmaf(w.w, h.w, acc[r].w);
        }
    }
    if (lane < 56) {                    // tail: 1656 = 25*64 + 56
        const int idx = 1600 + lane;
        const float4 h = sh4[idx];
        #pragma unroll
        for (int r = 0; r < NR; ++r) {
            const float4 w = Wr[r][idx];
            acc[r].x = fmaf(w.x, h.x, acc[r].x);
            acc[r].y = fmaf(w.y, h.y, acc[r].y);
            acc[r].z = fmaf(w.z, h.z, acc[r].z);
            acc[r].w = fmaf(w.w, h.w, acc[r].w);
        }
    }
    #pragma unroll
    for (int r = 0; r < NR; ++r) {
        float s = (acc[r].x + acc[r].y) + (acc[r].z + acc[r].w);
        #pragma unroll
        for (int off = 32; off > 0; off >>= 1) s += __shfl_xor(s, off, 64);
        if (lane == 0) hz_b[j0 + r] = tanhf(pv[r] + s);
    }
}

// ---------------------------------------------------------------------------
// Kernel C: 64 sequential RNN steps, grid barrier between steps.
//   h_b = tanh(pre[b] + h_{b-1} @ W_hh^T);  hz[b] = h_b  (biases in pre)
// Balanced floor-split: wave gw owns rows [(gw*69)>>5, ((gw+1)*69)>>5) —
// 2 or 3 rows, remainder spread uniformly -> per-CU load 25-26 rows.
// ---------------------------------------------------------------------------
__global__ __launch_bounds__(256, 3) void rnn_kernel(
    const float* __restrict__ Whh,      // (6624,6624)
    const float* __restrict__ pre,      // (64,6624) incl. b_ih+b_hh
    float* __restrict__ hz,             // (64,6624) output (also h chain)
    unsigned int* __restrict__ flags,   // RNN_BLOCKS slots, 64B apart
    int bar_base)
{
    const int lane = threadIdx.x & 63;
    const int widx = threadIdx.x >> 6;
    const int gw = blockIdx.x * 4 + widx;          // 0..3071
    const int r0 = (gw * 69) >> 5;                  // 6624/3072 = 69/32
    const int nr = (((gw + 1) * 69) >> 5) - r0;     // 2 or 3, wave-uniform

    __shared__ float4 sh4[H4];                      // 26.5 KB: h_{b-1}
    const float4* W4 = reinterpret_cast<const float4*>(Whh);

    for (int b = 0; b < 64; ++b) {
        const float* pre_b = pre + (size_t)b * HIDDEN;
        float* hz_b = hz + (size_t)b * HIDDEN;

        if (b > 0) {
            const float4* hrow = reinterpret_cast<const float4*>(hz + (size_t)(b - 1) * HIDDEN);
            for (int idx = threadIdx.x; idx < H4; idx += 256) sh4[idx] = hrow[idx];
        }
        __syncthreads();

        if (b == 0) {
            // h_{-1} = 0: matvec contributes nothing
            if (lane == 0)
                for (int r = 0; r < nr; ++r)
                    hz_b[r0 + r] = tanhf(pre_b[r0 + r]);
        } else if (nr == 2) {
            do_rows<2>(W4, r0, sh4, lane, pre_b, hz_b);
        } else {
            do_rows<3>(W4, r0, sh4, lane, pre_b, hz_b);
        }

        if (b != 63)
            grid_barrier(flags, (unsigned int)(bar_base + b + 1));
    }
}

// ---------------------------------------------------------------------------
extern "C" void kernel_launch(void* const* d_in, const int* in_sizes, int n_in,
                              void* d_out, int out_size, void* d_ws, size_t ws_size,
                              hipStream_t stream)
{
    const float* spline = (const float*)d_in[0];   // (12,64,207,2)
    const float* init0  = (const float*)d_in[1];   // (64,6624)
    const float* Wf     = (const float*)d_in[2];   // (16,32)
    const float* bf     = (const float*)d_in[3];   // (32,)
    const float* Wg     = (const float*)d_in[4];   // (16,256)
    const float* bg     = (const float*)d_in[5];   // (256,)
    const float* conv_w = (const float*)d_in[6];   // (16,)
    const float* Wih    = (const float*)d_in[7];   // (6624,16560)
    const float* b_ih   = (const float*)d_in[8];   // (6624,)
    const float* Whh    = (const float*)d_in[9];   // (6624,6624)
    const float* b_hh   = (const float*)d_in[10];  // (6624,)
    float* out = (float*)d_out;

    char* ws = (char*)d_ws;
    unsigned int* flags = (unsigned int*)ws;                       // 48 KB: 768 x 64B
    float* inpT  = (float*)(ws + 49152);                           // 4,239,360 B
    float* pre   = (float*)(ws + 49152 + (size_t)K_IH * 64 * 4);   // 1,695,744 B
    float* hz_ws = (float*)(ws + 49152 + (size_t)K_IH * 64 * 4
                                   + (size_t)BATCH * HIDDEN * 4);  // 1,695,744 B

    hipMemsetAsync(flags, 0, 49152, stream);

    for (int t = 0; t < TSTEPS; ++t) {
        const float* hz_in = (t == 0) ? init0 : hz_ws;
        float* hz_out = (t == TSTEPS - 1) ? out : hz_ws;

        build_inp_kernel<<<BATCH * NODE, 256, 0, stream>>>(
            spline, hz_in, Wf, bf, Wg, bg, conv_w, inpT, t);

        init_pre_kernel<<<(HIDDEN + 255) / 256, 256, 0, stream>>>(b_ih, b_hh, pre);

        gemm_ih_kernel<<<207 * 8, 256, 0, stream>>>(Wih, inpT, pre);

        rnn_kernel<<<RNN_BLOCKS, 256, 0, stream>>>(
            Whh, pre, hz_out, flags, t * 63);
    }
}

// Round 2
// 70515.576 us; speedup vs baseline: 1.3883x; 1.3883x over previous
//
#include <hip/hip_runtime.h>
#include <cstddef>
#include <cstdint>

#define NODE 207
#define HID 16
#define BATCH 64
#define TSTEPS 12
#define HIDDEN 6624            // NODE*HID*2
#define K_IH 16560             // NODE*HID*5
#define K_IH4 4140             // K_IH/4
#define H4 1656                // HIDDEN/4

// RNN grid: 768 blocks = exactly 3 blocks/CU on 256 CUs (co-resident:
// LDS 26.5KB*3 < 160KB, launch_bounds(256,3) caps VGPR ~170 -> 12 waves/CU).
#define RNN_BLOCKS 768

typedef float f32x4 __attribute__((ext_vector_type(4)));
typedef unsigned int u32x4 __attribute__((ext_vector_type(4)));

// ---- per-instruction coherent (cross-XCD) memory ops: sc0 sc1 = bypass
// ---- L1+L2, operate at the MALL (device coherent point). No fences needed.
__device__ __forceinline__ void store_wt(float* p, float v) {
    asm volatile("global_store_dword %0, %1, off sc0 sc1"
                 :: "v"(p), "v"(v) : "memory");
}
__device__ __forceinline__ f32x4 load_f4_nowait(const f32x4* p) {
    f32x4 v;
    asm volatile("global_load_dwordx4 %0, %1, off sc0 sc1"
                 : "=v"(v) : "v"(p) : "memory");
    return v;
}

// ---------------------------------------------------------------------------
// Kernel A: build transposed input inpT (K_IH, 64) for outer step t.
// One block per (b, n). inpT[k*64 + b]. (unchanged — trivial cost)
// ---------------------------------------------------------------------------
__global__ __launch_bounds__(256) void build_inp_kernel(
    const float* __restrict__ spline,   // (12,64,207,2)
    const float* __restrict__ hz,       // (64,6624)
    const float* __restrict__ Wf,       // (16,32)
    const float* __restrict__ bf,       // (32,)
    const float* __restrict__ Wg,       // (16,256)
    const float* __restrict__ bg,       // (256,)
    const float* __restrict__ conv_w,   // (16,)
    float* __restrict__ inpT,           // (16560,64)
    int t)
{
    const int bn = blockIdx.x;
    const int n = bn % NODE;
    const int b = bn / NODE;
    const int tid = threadIdx.x;

    __shared__ float shz[32];
    __shared__ float sf[32];
    __shared__ float sg[256];

    if (tid < 32) shz[tid] = hz[(size_t)b * HIDDEN + n * 32 + tid];
    __syncthreads();

    {
        float accg = bg[tid];
        #pragma unroll
        for (int i = 0; i < 16; ++i)
            accg = fmaf(shz[2 * i + 1], Wg[i * 256 + tid], accg);
        sg[tid] = tanhf(accg);
    }
    if (tid < 32) {
        float accf = bf[tid];
        #pragma unroll
        for (int i = 0; i < 16; ++i)
            accf = fmaf(shz[2 * i], Wf[i * 32 + tid], accf);
        float fv = tanhf(accf);
        sf[tid] = fv;
        int i2 = tid >> 1, kk = tid & 1;
        int kf = 3312 + n * 64 + i2 * 4 + kk * 2;      // s = 0
        inpT[(size_t)kf * 64 + b] = fv;
    } else if (tid < 48) {
        int i = tid - 32;
        float v = spline[((((size_t)t * BATCH + b) * NODE + n) * 2) + 1];
        inpT[(size_t)(i * NODE + n) * 64 + b] = conv_w[i] * v;
    }
    __syncthreads();
    if (tid < 32) {
        int i2 = tid >> 1, kk = tid & 1;
        float acc = 0.f;
        #pragma unroll
        for (int j = 0; j < 16; ++j)
            acc = fmaf(sg[i2 * 16 + j], sf[j * 2 + kk], acc);
        int kfg = 3312 + n * 64 + i2 * 4 + kk * 2 + 1; // s = 1
        inpT[(size_t)kfg * 64 + b] = acc;
    }
}

// ---------------------------------------------------------------------------
// Kernel B: pre[b][j] = bias_j + sum_k inp[b,k] * W_ih[j,k].
// Grid: 207 j-tiles (32 rows). Block: 512 thr = 64 b-lanes x 8 k-parts.
// In-block k-split: NO atomics, no init kernel. W_ih read exactly once.
// ---------------------------------------------------------------------------
__global__ __launch_bounds__(512) void gemm_ih_kernel(
    const float* __restrict__ Wih,      // (6624,16560)
    const float* __restrict__ inpT,     // (16560,64)
    const float* __restrict__ b_ih,     // (6624,)
    const float* __restrict__ b_hh,     // (6624,)
    float* __restrict__ pre)            // (64,6624)
{
    const int j0 = blockIdx.x * 32;
    const int tid = threadIdx.x;
    const int b = tid & 63;
    const int p = tid >> 6;             // 0..7 (wave-uniform)

    float acc[32];
    #pragma unroll
    for (int jj = 0; jj < 32; ++jj) acc[jj] = 0.f;

    for (int g = p; g < K_IH4; g += 8) {
        const int k = g * 4;
        const float v0 = inpT[(size_t)(k + 0) * 64 + b];
        const float v1 = inpT[(size_t)(k + 1) * 64 + b];
        const float v2 = inpT[(size_t)(k + 2) * 64 + b];
        const float v3 = inpT[(size_t)(k + 3) * 64 + b];
        #pragma unroll
        for (int jj = 0; jj < 32; ++jj) {
            const float4 w = *reinterpret_cast<const float4*>(
                Wih + (size_t)(j0 + jj) * K_IH + k);
            acc[jj] = fmaf(w.x, v0, fmaf(w.y, v1, fmaf(w.z, v2, fmaf(w.w, v3, acc[jj]))));
        }
    }

    __shared__ float red[8][32][65];    // 66.6 KB, +1 pad vs bank conflicts
    #pragma unroll
    for (int jj = 0; jj < 32; ++jj) red[p][jj][b] = acc[jj];
    __syncthreads();

    for (int idx = tid; idx < 2048; idx += 512) {
        const int jj = idx & 31;
        const int b2 = idx >> 5;
        float s = 0.f;
        #pragma unroll
        for (int q = 0; q < 8; ++q) s += red[q][jj][b2];
        pre[(size_t)b2 * HIDDEN + j0 + jj] = s + b_ih[j0 + jj] + b_hh[j0 + jj];
    }
}

// ---------------------------------------------------------------------------
// NR rows per wave, depth-2 W-prefetch pipeline. h from LDS; pre prefetched.
// ---------------------------------------------------------------------------
template<int NR>
__device__ __forceinline__ void do_rows(const f32x4* __restrict__ W4, int j0,
                                        const f32x4* sh4, int lane,
                                        const float* __restrict__ pre_b,
                                        float* __restrict__ hz_b)
{
    const f32x4* Wr[NR];
    f32x4 wc[NR], acc[NR];
    float pv[NR];
    #pragma unroll
    for (int r = 0; r < NR; ++r) {
        Wr[r] = W4 + (size_t)(j0 + r) * H4;
        wc[r] = Wr[r][lane];                    // prologue load (it = 0)
        acc[r] = f32x4{0.f, 0.f, 0.f, 0.f};
        pv[r] = pre_b[j0 + r];                  // broadcast load
    }
    #pragma unroll 4
    for (int it = 0; it < 24; ++it) {
        f32x4 wn[NR];
        #pragma unroll
        for (int r = 0; r < NR; ++r) wn[r] = Wr[r][it * 64 + 64 + lane];
        const f32x4 h = sh4[it * 64 + lane];
        #pragma unroll
        for (int r = 0; r < NR; ++r) {
            acc[r].x = fmaf(wc[r].x, h.x, acc[r].x);
            acc[r].y = fmaf(wc[r].y, h.y, acc[r].y);
            acc[r].z = fmaf(wc[r].z, h.z, acc[r].z);
            acc[r].w = fmaf(wc[r].w, h.w, acc[r].w);
        }
        #pragma unroll
        for (int r = 0; r < NR; ++r) wc[r] = wn[r];
    }
    {   // it = 24, + tail (1656 = 25*64 + 56)
        const bool tl = lane < 56;
        f32x4 wn[NR];
        if (tl) {
            #pragma unroll
            for (int r = 0; r < NR; ++r) wn[r] = Wr[r][1600 + lane];
        }
        const f32x4 h = sh4[24 * 64 + lane];
        #pragma unroll
        for (int r = 0; r < NR; ++r) {
            acc[r].x = fmaf(wc[r].x, h.x, acc[r].x);
            acc[r].y = fmaf(wc[r].y, h.y, acc[r].y);
            acc[r].z = fmaf(wc[r].z, h.z, acc[r].z);
            acc[r].w = fmaf(wc[r].w, h.w, acc[r].w);
        }
        if (tl) {
            const f32x4 h2 = sh4[1600 + lane];
            #pragma unroll
            for (int r = 0; r < NR; ++r) {
                acc[r].x = fmaf(wn[r].x, h2.x, acc[r].x);
                acc[r].y = fmaf(wn[r].y, h2.y, acc[r].y);
                acc[r].z = fmaf(wn[r].z, h2.z, acc[r].z);
                acc[r].w = fmaf(wn[r].w, h2.w, acc[r].w);
            }
        }
    }
    #pragma unroll
    for (int r = 0; r < NR; ++r) {
        float s = (acc[r].x + acc[r].y) + (acc[r].z + acc[r].w);
        #pragma unroll
        for (int off = 32; off > 0; off >>= 1) s += __shfl_xor(s, off, 64);
        if (lane == 0) store_wt(hz_b + j0 + r, tanhf(pv[r] + s));
    }
}

// ---------------------------------------------------------------------------
// Kernel C: 64 sequential RNN steps. NO fences in the loop:
//  - h stores write-through (sc0 sc1) to the coherent point
//  - h staging loads bypass (sc0 sc1)
//  - barrier = contiguous flag array; ONLY wave 0 polls, 3 coalesced
//    dwordx4 bypass loads per sweep (48 line-reqs/block vs 192 scattered).
// W_hh / pre stay in L1/L2 across steps (never invalidated).
// ---------------------------------------------------------------------------
__global__ __launch_bounds__(256, 3) void rnn_kernel(
    const float* __restrict__ Whh,      // (6624,6624)
    const float* __restrict__ pre,      // (64,6624) incl. b_ih+b_hh
    float* __restrict__ hz,             // (64,6624) output (also h chain)
    unsigned int* __restrict__ flags,   // RNN_BLOCKS contiguous u32
    int bar_base)
{
    const int tid = threadIdx.x;
    const int lane = tid & 63;
    const int widx = tid >> 6;
    const int gw = blockIdx.x * 4 + widx;          // 0..3071
    const int r0 = (gw * 69) >> 5;                  // 6624/3072 = 69/32
    const int nr = (((gw + 1) * 69) >> 5) - r0;     // 2 or 3, wave-uniform

    __shared__ f32x4 sh4[H4];                       // 26.5 KB: h_{b-1}
    const f32x4* W4 = reinterpret_cast<const f32x4*>(Whh);

    for (int b = 0; b < 64; ++b) {
        if (b > 0) {
            // stage h_{b-1} via cache-bypass loads, 7-deep then one wait
            const f32x4* hp = reinterpret_cast<const f32x4*>(
                hz + (size_t)(b - 1) * HIDDEN);
            f32x4 t0 = load_f4_nowait(hp + tid);
            f32x4 t1 = load_f4_nowait(hp + tid + 256);
            f32x4 t2 = load_f4_nowait(hp + tid + 512);
            f32x4 t3 = load_f4_nowait(hp + tid + 768);
            f32x4 t4 = load_f4_nowait(hp + tid + 1024);
            f32x4 t5 = load_f4_nowait(hp + tid + 1280);
            const bool has7 = tid < (H4 - 1536);    // tid < 120
            f32x4 t6;
            if (has7) t6 = load_f4_nowait(hp + tid + 1536);
            asm volatile("s_waitcnt vmcnt(0)" ::: "memory");
            __builtin_amdgcn_sched_barrier(0);
            sh4[tid]        = t0;
            sh4[tid + 256]  = t1;
            sh4[tid + 512]  = t2;
            sh4[tid + 768]  = t3;
            sh4[tid + 1024] = t4;
            sh4[tid + 1280] = t5;
            if (has7) sh4[tid + 1536] = t6;
        }
        __syncthreads();

        const float* pre_b = pre + (size_t)b * HIDDEN;
        float* hz_b = hz + (size_t)b * HIDDEN;

        if (b == 0) {
            // h_{-1} = 0: matvec contributes nothing
            if (lane == 0)
                for (int r = 0; r < nr; ++r)
                    store_wt(hz_b + r0 + r, tanhf(pre_b[r0 + r]));
        } else if (nr == 2) {
            do_rows<2>(W4, r0, sh4, lane, pre_b, hz_b);
        } else {
            do_rows<3>(W4, r0, sh4, lane, pre_b, hz_b);
        }

        if (b != 63) {
            // drain this wave's write-through stores, then block-wide sync
            asm volatile("s_waitcnt vmcnt(0)" ::: "memory");
            __syncthreads();
            if (widx == 0) {
                const unsigned int e = (unsigned int)(bar_base + b + 1);
                if (lane == 0)
                    asm volatile("global_store_dword %0, %1, off sc0 sc1"
                                 :: "v"(flags + blockIdx.x), "v"(e) : "memory");
                const unsigned int* pb = flags + lane * 12;   // 12 contiguous
                for (;;) {
                    u32x4 f0, f1, f2;
                    asm volatile(
                        "global_load_dwordx4 %0, %3, off sc0 sc1\n\t"
                        "global_load_dwordx4 %1, %3, off offset:16 sc0 sc1\n\t"
                        "global_load_dwordx4 %2, %3, off offset:32 sc0 sc1\n\t"
                        "s_waitcnt vmcnt(0)"
                        : "=v"(f0), "=v"(f1), "=v"(f2)
                        : "v"(pb) : "memory");
                    const bool ok =
                        f0[0] >= e && f0[1] >= e && f0[2] >= e && f0[3] >= e &&
                        f1[0] >= e && f1[1] >= e && f1[2] >= e && f1[3] >= e &&
                        f2[0] >= e && f2[1] >= e && f2[2] >= e && f2[3] >= e;
                    if (__all(ok)) break;
                    __builtin_amdgcn_s_sleep(4);
                }
            }
            __syncthreads();
        }
    }
}

// ---------------------------------------------------------------------------
extern "C" void kernel_launch(void* const* d_in, const int* in_sizes, int n_in,
                              void* d_out, int out_size, void* d_ws, size_t ws_size,
                              hipStream_t stream)
{
    const float* spline = (const float*)d_in[0];   // (12,64,207,2)
    const float* init0  = (const float*)d_in[1];   // (64,6624)
    const float* Wf     = (const float*)d_in[2];   // (16,32)
    const float* bf     = (const float*)d_in[3];   // (32,)
    const float* Wg     = (const float*)d_in[4];   // (16,256)
    const float* bg     = (const float*)d_in[5];   // (256,)
    const float* conv_w = (const float*)d_in[6];   // (16,)
    const float* Wih    = (const float*)d_in[7];   // (6624,16560)
    const float* b_ih   = (const float*)d_in[8];   // (6624,)
    const float* Whh    = (const float*)d_in[9];   // (6624,6624)
    const float* b_hh   = (const float*)d_in[10];  // (6624,)
    float* out = (float*)d_out;

    char* ws = (char*)d_ws;
    unsigned int* flags = (unsigned int*)ws;                      // 4 KB
    float* inpT  = (float*)(ws + 4096);                           // 4,239,360 B
    float* pre   = (float*)(ws + 4096 + (size_t)K_IH * 64 * 4);   // 1,695,744 B
    float* hz_ws = (float*)(ws + 4096 + (size_t)K_IH * 64 * 4
                                  + (size_t)BATCH * HIDDEN * 4);  // 1,695,744 B

    hipMemsetAsync(flags, 0, 4096, stream);

    for (int t = 0; t < TSTEPS; ++t) {
        const float* hz_in = (t == 0) ? init0 : hz_ws;
        float* hz_out = (t == TSTEPS - 1) ? out : hz_ws;

        build_inp_kernel<<<BATCH * NODE, 256, 0, stream>>>(
            spline, hz_in, Wf, bf, Wg, bg, conv_w, inpT, t);

        gemm_ih_kernel<<<207, 512, 0, stream>>>(Wih, inpT, b_ih, b_hh, pre);

        rnn_kernel<<<RNN_BLOCKS, 256, 0, stream>>>(
            Whh, pre, hz_out, flags, t * 63);
    }
}